// Round 10
// baseline (164.048 us; speedup 1.0000x reference)
//
#include <hip/hip_runtime.h>

// GraphSAGE (2 SAGEConv mean-agg layers + linear head) on MI355X.
// N=100000 nodes, E=1600000 edges, D=64 channels, OUT=32.
//
// Round-10:
//  * gather: 16 outstanding dword-pair loads (16-slot batches + 8-slot tail,
//    pairs is always a multiple of 8). Slots j/j+8 share accumulators ->
//    VGPR stays <=64, occupancy 8 preserved. No extra pad traffic.
//  * bin+prep fusion, fixed-capacity CSR, dense MFMA unchanged (verified).

#define D 64
#define OUTD 32
#define REG_SHIFT 8
#define REG_SIZE 256
#define BCHUNK 4096
#define PADQ 16                  // pad node lists to multiple of 16
#define CAP 5120                 // ebuf capacity per region (mean 4092, sigma 64)
#define OUTCAP 8960              // colP capacity per region

// ---------------- workspace layout (int units), ~61.7 MB of 256 MiB ----------------
#define OFF_FLAG     0          // 64
#define OFF_RCUR     64         // 512
#define OFF_DEG      576        // N padded-deg (reserve 100352)
#define OFF_ROWSTART 100928     // N
#define OFF_INV      201280     // N floats
#define OFF_COL      301632     // 391*OUTCAP = 3503360
#define OFF_EBUF     3804992    // 391*CAP = 2001920
#define OFF_XB       5806912    // (N+1)*32
#define OFF_H1B      9006944    // (N+1)*32
#define OFF_MEANB    12206976   // N*32
#define OFF_WC1      15406976   // 4096
#define OFF_WC2      15411072   // 4096
#define OFF_WHB      15415168   // 1024

typedef __attribute__((ext_vector_type(8))) short bf16x8;
typedef __attribute__((ext_vector_type(4))) float f32x4;

__device__ __forceinline__ unsigned short bf16rne(float x) {
    unsigned u = __float_as_uint(x);
    unsigned r = (u + 0x7FFFu + ((u >> 16) & 1u)) >> 16;
    return (unsigned short)r;
}

// Detect int64-vs-int32 edge layout + init per-region cursors to r*CAP.
__global__ void detect_init(const int* __restrict__ e32, int* __restrict__ flag,
                            int* __restrict__ rcur, int NR) {
    int t = threadIdx.x;                 // 512 threads
    if (t < 64) {
        int v = e32[2 * t + 1];
        unsigned long long m = __ballot(v != 0);
        if (t == 0) flag[0] = (m == 0ULL) ? 1 : 0;   // 1 => int64 layout
    }
    if (t < NR) rcur[t] = t * CAP;
}

// Fused: blocks < bblocks bin edges into region segments; the rest do prep
// (fp32->bf16 cast of x, zero rows, weight concat). Independent outputs.
__global__ __launch_bounds__(256) void bin_prep(
        const int* __restrict__ e32, const int* __restrict__ flag,
        int* __restrict__ rcur, int* __restrict__ ebuf, int E, int NR, int bblocks,
        const float* __restrict__ x, unsigned short* __restrict__ xb,
        unsigned short* __restrict__ h1b,
        const float* __restrict__ w1l, const float* __restrict__ w1r,
        const float* __restrict__ w2l, const float* __restrict__ w2r,
        const float* __restrict__ wh,
        unsigned short* __restrict__ wcat1, unsigned short* __restrict__ wcat2,
        unsigned short* __restrict__ whb, int n4, int N) {
    __shared__ int stage[BCHUNK];
    __shared__ unsigned short rgn[BCHUNK];
    __shared__ int hist[512], lbase[512], startr[512], s1[512];
    int t = threadIdx.x;

    if (blockIdx.x >= bblocks) {
        // ---------------- prep path ----------------
        int i = (blockIdx.x - bblocks) * 256 + t;
        if (i < n4) {
            float4 v = ((const float4*)x)[i];
            unsigned lo = (unsigned)bf16rne(v.x) | ((unsigned)bf16rne(v.y) << 16);
            unsigned hi = (unsigned)bf16rne(v.z) | ((unsigned)bf16rne(v.w) << 16);
            ((uint2*)xb)[i] = make_uint2(lo, hi);
            return;
        }
        int j = i - n4;
        if (j < 16) {
            ((uint2*)xb)[(size_t)N * 16 + j] = make_uint2(0u, 0u);
        } else if (j < 32) {
            ((uint2*)h1b)[(size_t)N * 16 + (j - 16)] = make_uint2(0u, 0u);
        } else if (j < 32 + 8192) {
            int q = j - 32;
            int o = q >> 7, k = q & 127;
            wcat1[q] = bf16rne(k < 64 ? w1l[o * 64 + k] : w1r[o * 64 + k - 64]);
        } else if (j < 32 + 16384) {
            int q = j - 32 - 8192;
            int o = q >> 7, k = q & 127;
            wcat2[q] = bf16rne(k < 64 ? w2l[o * 64 + k] : w2r[o * 64 + k - 64]);
        } else if (j < 32 + 16384 + 2048) {
            int q = j - 32 - 16384;
            whb[q] = bf16rne(wh[q]);
        }
        return;
    }

    // ---------------- bin path ----------------
    int mode = flag[0];
    int base = blockIdx.x * BCHUNK;
    for (int i = t; i < 512; i += 256) hist[i] = 0;
    __syncthreads();
    for (int j = t; j < BCHUNK; j += 256) {
        int i = base + j;
        if (i < E) {
            int d = mode ? e32[2 * (E + i)] : e32[E + i];
            atomicAdd(&hist[d >> REG_SHIFT], 1);
        }
    }
    __syncthreads();
    {
        int* a = lbase; int* b = s1;
        for (int i = t; i < 512; i += 256) a[i] = hist[i];
        __syncthreads();
        for (int off = 1; off < 512; off <<= 1) {
            for (int i = t; i < 512; i += 256)
                b[i] = a[i] + ((i >= off) ? a[i - off] : 0);
            __syncthreads();
            int* tmp = a; a = b; b = tmp;
        }
        for (int i = t; i < 512; i += 256) {
            int incl = a[i];
            int ex = incl - hist[i];
            __syncthreads();
            lbase[i] = ex;
        }
        __syncthreads();
    }
    for (int i = t; i < 512; i += 256) {
        int st = 0;
        if (i < NR && hist[i] > 0) {
            st = atomicAdd(&rcur[i], hist[i]);
            int lim = (i + 1) * CAP - hist[i];
            if (st > lim) st = lim;            // safety clamp (won't trigger)
        }
        startr[i] = st;
    }
    __syncthreads();
    for (int i = t; i < 512; i += 256) hist[i] = 0;
    __syncthreads();
    for (int j = t; j < BCHUNK; j += 256) {
        int i = base + j;
        if (i < E) {
            int s = mode ? e32[2 * i]       : e32[i];
            int d = mode ? e32[2 * (E + i)] : e32[E + i];
            int r = d >> REG_SHIFT;
            int o = atomicAdd(&hist[r], 1);
            int pos = lbase[r] + o;
            stage[pos] = ((d & (REG_SIZE - 1)) << 24) | s;
            rgn[pos] = (unsigned short)r;
        }
    }
    __syncthreads();
    int count = E - base; if (count > BCHUNK) count = BCHUNK;
    for (int i = t; i < count; i += 256) {
        int r = rgn[i];
        ebuf[startr[r] + (i - lbase[r])] = stage[i];
    }
}

// Per-region local CSR build with zero-row padding (byte offsets, x16 pad).
__global__ __launch_bounds__(256) void build_csr(
        const int* __restrict__ ebuf, const int* __restrict__ rcur,
        int* __restrict__ degP, int* __restrict__ rowStartP, float* __restrict__ inv,
        int* __restrict__ colP, int N) {
    __shared__ int hist[REG_SIZE], cur[REG_SIZE], sA[REG_SIZE], sB[REG_SIZE];
    int r = blockIdx.x;
    int t = threadIdx.x;
    int lo = r << REG_SHIFT;
    int e0 = r * CAP, e1 = rcur[r];
    int colPbase = r * OUTCAP;
    hist[t] = 0;
    __syncthreads();
    for (int i = e0 + t; i < e1; i += 256)
        atomicAdd(&hist[((unsigned)ebuf[i]) >> 24], 1);
    __syncthreads();
    int v = hist[t];
    int vp = (v + PADQ - 1) & ~(PADQ - 1);
    int* a = sA; int* b = sB;
    a[t] = vp;
    __syncthreads();
    for (int off = 1; off < 256; off <<= 1) {
        b[t] = a[t] + ((t >= off) ? a[t - off] : 0);
        __syncthreads();
        int* tmp = a; a = b; b = tmp;
    }
    int startP = colPbase + (a[t] - vp);
    int node = lo + t;
    if (node < N) {
        degP[node] = vp;
        rowStartP[node] = startP;
        inv[node] = 1.0f / (float)(v > 0 ? v : 1);
    }
    cur[t] = startP;
    __syncthreads();
    for (int i = e0 + t; i < e1; i += 256) {
        int p = ebuf[i];
        int pos = atomicAdd(&cur[((unsigned)p) >> 24], 1);
        colP[pos] = (p & 0xFFFFFF) << 7;        // byte offset
    }
    __syncthreads();
    int zoff = N << 7;
    for (int k = startP + v; k < startP + vp; ++k) colP[k] = zoff;
}

// Gather: one node per wave. Dword-pair loads: lanes 0-31 cover the even
// neighbor's 128B row, lanes 32-63 the odd one's (uint = 2 channels/lane).
// 16 loads in flight (16-slot batches + 8-slot tail; pairs % 8 == 0).
// Slots j and j+8 share accumulators. Lists padded with the zero row.
__global__ __launch_bounds__(256, 8) void gather_mean_bf16(
        const unsigned short* __restrict__ hb, const int* __restrict__ rowStartP,
        const int* __restrict__ degPv, const int* __restrict__ colP,
        const float* __restrict__ invdeg, unsigned short* __restrict__ meanb,
        int n) {
    int wid = (blockIdx.x * 256 + (int)threadIdx.x) >> 6;
    int lane = threadIdx.x & 63;
    if (wid >= n) return;
    int node = __builtin_amdgcn_readfirstlane(wid);

    int rs = rowStartP[node];
    int dgp = degPv[node];
    const char* hbC = (const char*)hb;
    int half = lane >> 5, l31 = lane & 31;
    int voff = l31 << 2;

    float aL0 = 0.f, aL1 = 0.f, aL2 = 0.f, aL3 = 0.f;
    float aL4 = 0.f, aL5 = 0.f, aL6 = 0.f, aL7 = 0.f;
    float aH0 = 0.f, aH1 = 0.f, aH2 = 0.f, aH3 = 0.f;
    float aH4 = 0.f, aH5 = 0.f, aH6 = 0.f, aH7 = 0.f;

#define LO(u) __uint_as_float((u) << 16)
#define HI(u) __uint_as_float((u) & 0xFFFF0000u)

    for (int base = 0; base < dgp; base += 64) {
        int cv = colP[rs + base + lane];
        int m = dgp - base; if (m > 64) m = 64;
        int pairs = m >> 1;                 // multiple of 8
        int p = 0;
        for (; p + 16 <= pairs; p += 16) {
            int c0  = __shfl(cv, 2 * (p + 0)  + half);
            int c1  = __shfl(cv, 2 * (p + 1)  + half);
            int c2  = __shfl(cv, 2 * (p + 2)  + half);
            int c3  = __shfl(cv, 2 * (p + 3)  + half);
            int c4  = __shfl(cv, 2 * (p + 4)  + half);
            int c5  = __shfl(cv, 2 * (p + 5)  + half);
            int c6  = __shfl(cv, 2 * (p + 6)  + half);
            int c7  = __shfl(cv, 2 * (p + 7)  + half);
            int c8  = __shfl(cv, 2 * (p + 8)  + half);
            int c9  = __shfl(cv, 2 * (p + 9)  + half);
            int c10 = __shfl(cv, 2 * (p + 10) + half);
            int c11 = __shfl(cv, 2 * (p + 11) + half);
            int c12 = __shfl(cv, 2 * (p + 12) + half);
            int c13 = __shfl(cv, 2 * (p + 13) + half);
            int c14 = __shfl(cv, 2 * (p + 14) + half);
            int c15 = __shfl(cv, 2 * (p + 15) + half);
            unsigned u0  = *(const unsigned*)(hbC + c0  + voff);
            unsigned u1  = *(const unsigned*)(hbC + c1  + voff);
            unsigned u2  = *(const unsigned*)(hbC + c2  + voff);
            unsigned u3  = *(const unsigned*)(hbC + c3  + voff);
            unsigned u4  = *(const unsigned*)(hbC + c4  + voff);
            unsigned u5  = *(const unsigned*)(hbC + c5  + voff);
            unsigned u6  = *(const unsigned*)(hbC + c6  + voff);
            unsigned u7  = *(const unsigned*)(hbC + c7  + voff);
            unsigned u8  = *(const unsigned*)(hbC + c8  + voff);
            unsigned u9  = *(const unsigned*)(hbC + c9  + voff);
            unsigned u10 = *(const unsigned*)(hbC + c10 + voff);
            unsigned u11 = *(const unsigned*)(hbC + c11 + voff);
            unsigned u12 = *(const unsigned*)(hbC + c12 + voff);
            unsigned u13 = *(const unsigned*)(hbC + c13 + voff);
            unsigned u14 = *(const unsigned*)(hbC + c14 + voff);
            unsigned u15 = *(const unsigned*)(hbC + c15 + voff);
            aL0 += LO(u0);  aH0 += HI(u0);
            aL1 += LO(u1);  aH1 += HI(u1);
            aL2 += LO(u2);  aH2 += HI(u2);
            aL3 += LO(u3);  aH3 += HI(u3);
            aL4 += LO(u4);  aH4 += HI(u4);
            aL5 += LO(u5);  aH5 += HI(u5);
            aL6 += LO(u6);  aH6 += HI(u6);
            aL7 += LO(u7);  aH7 += HI(u7);
            aL0 += LO(u8);  aH0 += HI(u8);
            aL1 += LO(u9);  aH1 += HI(u9);
            aL2 += LO(u10); aH2 += HI(u10);
            aL3 += LO(u11); aH3 += HI(u11);
            aL4 += LO(u12); aH4 += HI(u12);
            aL5 += LO(u13); aH5 += HI(u13);
            aL6 += LO(u14); aH6 += HI(u14);
            aL7 += LO(u15); aH7 += HI(u15);
        }
        if (pairs & 8) {
#define G(j, AL, AH) { \
            int cb = __shfl(cv, 2 * (p + (j)) + half); \
            unsigned u = *(const unsigned*)(hbC + cb + voff); \
            AL += LO(u); \
            AH += HI(u); }
            G(0, aL0, aH0)  G(1, aL1, aH1)  G(2, aL2, aH2)  G(3, aL3, aH3)
            G(4, aL4, aH4)  G(5, aL5, aH5)  G(6, aL6, aH6)  G(7, aL7, aH7)
#undef G
        }
    }
#undef LO
#undef HI
    float s0 = ((aL0 + aL1) + (aL2 + aL3)) + ((aL4 + aL5) + (aL6 + aL7));
    float s1 = ((aH0 + aH1) + (aH2 + aH3)) + ((aH4 + aH5) + (aH6 + aH7));
    s0 += __shfl_xor(s0, 32);
    s1 += __shfl_xor(s1, 32);
    float iv = invdeg[node];
    if (!half) {
        unsigned mo = (unsigned)bf16rne(s0 * iv) | ((unsigned)bf16rne(s1 * iv) << 16);
        ((unsigned*)meanb)[(size_t)node * 32 + l31] = mo;
    }
}

// Dense via MFMA (verified rounds 5-9). One 16-node tile per wave iteration.
template <bool HEAD>
__global__ __launch_bounds__(256, 2) void dense_mfma(
        const unsigned short* __restrict__ meanb,
        const unsigned short* __restrict__ ownb,
        const unsigned short* __restrict__ wcat,   // [64][128]
        const float* __restrict__ bias,            // [64]
        unsigned short* __restrict__ houtb,        // !HEAD out (bf16)
        const unsigned short* __restrict__ whb,    // [32][64]
        const float* __restrict__ bh,              // [32]
        float* __restrict__ outp,                  // [N][32]
        int n) {
    const int lane = threadIdx.x & 63;
    const int wave = threadIdx.x >> 6;
    const int l15 = lane & 15;
    const int kg  = lane >> 4;

    bf16x8 Bf[4][4];
#pragma unroll
    for (int nt = 0; nt < 4; ++nt)
#pragma unroll
        for (int s = 0; s < 4; ++s)
            Bf[nt][s] = *(const bf16x8*)(wcat + (nt * 16 + l15) * 128 + s * 32 + kg * 8);

    float biasc[4];
#pragma unroll
    for (int nt = 0; nt < 4; ++nt) biasc[nt] = bias[nt * 16 + l15];

    bf16x8 Hf[2][2];
    float bhc[2];
    if constexpr (HEAD) {
#pragma unroll
        for (int nt = 0; nt < 2; ++nt) {
#pragma unroll
            for (int s = 0; s < 2; ++s)
                Hf[nt][s] = *(const bf16x8*)(whb + (nt * 16 + l15) * 64 + s * 32 + kg * 8);
            bhc[nt] = bh[nt * 16 + l15];
        }
    }

    __shared__ unsigned short hlds[HEAD ? 4 * 16 * 64 : 64];

    const int ntiles = (n + 15) >> 4;
    const int stride = gridDim.x * 4;
    int tile = blockIdx.x * 4 + wave;
    if (tile >= ntiles) return;

    bf16x8 Ac[4], An[4];
    {
        int row = tile * 16 + l15; if (row >= n) row = n - 1;
        const unsigned short* mrow = meanb + (size_t)row * 64 + kg * 8;
        const unsigned short* orow = ownb  + (size_t)row * 64 + kg * 8;
        Ac[0] = *(const bf16x8*)(mrow);
        Ac[1] = *(const bf16x8*)(mrow + 32);
        Ac[2] = *(const bf16x8*)(orow);
        Ac[3] = *(const bf16x8*)(orow + 32);
    }

    while (true) {
        int nxt = tile + stride;
        bool hasNext = nxt < ntiles;
        if (hasNext) {
            int row = nxt * 16 + l15; if (row >= n) row = n - 1;
            const unsigned short* mrow = meanb + (size_t)row * 64 + kg * 8;
            const unsigned short* orow = ownb  + (size_t)row * 64 + kg * 8;
            An[0] = *(const bf16x8*)(mrow);
            An[1] = *(const bf16x8*)(mrow + 32);
            An[2] = *(const bf16x8*)(orow);
            An[3] = *(const bf16x8*)(orow + 32);
        }

        f32x4 acc[4];
#pragma unroll
        for (int nt = 0; nt < 4; ++nt) {
            f32x4 a = {biasc[nt], biasc[nt], biasc[nt], biasc[nt]};
            a = __builtin_amdgcn_mfma_f32_16x16x32_bf16(Ac[0], Bf[nt][0], a, 0, 0, 0);
            a = __builtin_amdgcn_mfma_f32_16x16x32_bf16(Ac[1], Bf[nt][1], a, 0, 0, 0);
            a = __builtin_amdgcn_mfma_f32_16x16x32_bf16(Ac[2], Bf[nt][2], a, 0, 0, 0);
            a = __builtin_amdgcn_mfma_f32_16x16x32_bf16(Ac[3], Bf[nt][3], a, 0, 0, 0);
            acc[nt] = a;
        }

        int nb = tile * 16;
        if constexpr (!HEAD) {
#pragma unroll
            for (int nt = 0; nt < 4; ++nt)
#pragma unroll
                for (int r = 0; r < 4; ++r) {
                    int row = nb + kg * 4 + r;
                    float h = fmaxf(acc[nt][r], 0.0f);
                    if (row < n) houtb[(size_t)row * 64 + nt * 16 + l15] = bf16rne(h);
                }
        } else {
            unsigned short* L = hlds + wave * 1024;
            int n7 = lane & 7;
#pragma unroll
            for (int nt = 0; nt < 4; ++nt) {
                int bGlob = nt * 2 + (l15 >> 3);
#pragma unroll
                for (int r = 0; r < 4; ++r) {
                    int m = kg * 4 + r;
                    float h = fmaxf(acc[nt][r], 0.0f);
                    L[m * 64 + ((bGlob ^ (m & 7)) * 8) + n7] = bf16rne(h);
                }
            }
            __builtin_amdgcn_wave_barrier();
            bf16x8 hA[2];
#pragma unroll
            for (int s = 0; s < 2; ++s) {
                int kb = s * 4 + kg;
                hA[s] = *(const bf16x8*)(L + l15 * 64 + ((kb ^ (l15 & 7)) * 8));
            }
            __builtin_amdgcn_wave_barrier();
            f32x4 acc2[2];
#pragma unroll
            for (int nt = 0; nt < 2; ++nt) {
                f32x4 a = {bhc[nt], bhc[nt], bhc[nt], bhc[nt]};
                a = __builtin_amdgcn_mfma_f32_16x16x32_bf16(hA[0], Hf[nt][0], a, 0, 0, 0);
                a = __builtin_amdgcn_mfma_f32_16x16x32_bf16(hA[1], Hf[nt][1], a, 0, 0, 0);
                acc2[nt] = a;
            }
#pragma unroll
            for (int nt = 0; nt < 2; ++nt)
#pragma unroll
                for (int r = 0; r < 4; ++r) {
                    int row = nb + kg * 4 + r;
                    if (row < n) outp[(size_t)row * 32 + nt * 16 + l15] = acc2[nt][r];
                }
        }

        if (!hasNext) break;
        tile = nxt;
#pragma unroll
        for (int q = 0; q < 4; ++q) Ac[q] = An[q];
    }
}

extern "C" void kernel_launch(void* const* d_in, const int* in_sizes, int n_in,
                              void* d_out, int out_size, void* d_ws, size_t ws_size,
                              hipStream_t stream) {
    const float* x   = (const float*)d_in[0];
    const int* edges = (const int*)d_in[1];
    const float* w1l = (const float*)d_in[2];
    const float* b1  = (const float*)d_in[3];
    const float* w1r = (const float*)d_in[4];
    const float* w2l = (const float*)d_in[5];
    const float* b2  = (const float*)d_in[6];
    const float* w2r = (const float*)d_in[7];
    const float* wh  = (const float*)d_in[8];
    const float* bh  = (const float*)d_in[9];
    float* out = (float*)d_out;

    const int N = in_sizes[0] / D;   // 100000
    const int E = in_sizes[1] / 2;   // 1600000
    const int NR = (N + REG_SIZE - 1) >> REG_SHIFT;   // 391

    int* ws = (int*)d_ws;
    int*            flag     = ws + OFF_FLAG;
    int*            rcur     = ws + OFF_RCUR;
    int*            degP     = ws + OFF_DEG;
    int*            rowStartP= ws + OFF_ROWSTART;
    float*          inv      = (float*)(ws + OFF_INV);
    int*            colP     = ws + OFF_COL;
    int*            ebuf     = ws + OFF_EBUF;
    unsigned short* xb       = (unsigned short*)(ws + OFF_XB);
    unsigned short* h1b      = (unsigned short*)(ws + OFF_H1B);
    unsigned short* meanb    = (unsigned short*)(ws + OFF_MEANB);
    unsigned short* wcat1    = (unsigned short*)(ws + OFF_WC1);
    unsigned short* wcat2    = (unsigned short*)(ws + OFF_WC2);
    unsigned short* whb      = (unsigned short*)(ws + OFF_WHB);

    // ---- CSR build + prep (bin and prep fused into one dispatch) ----
    detect_init<<<1, 512, 0, stream>>>(edges, flag, rcur, NR);
    int bblocks = (E + BCHUNK - 1) / BCHUNK;                  // 391
    int n4 = N * D / 4;
    int pblocks = (n4 + 32 + 16384 + 2048 + 255) / 256;       // ~6323
    bin_prep<<<bblocks + pblocks, 256, 0, stream>>>(
        edges, flag, rcur, ebuf, E, NR, bblocks,
        x, xb, h1b, w1l, w1r, w2l, w2r, wh, wcat1, wcat2, whb, n4, N);
    build_csr<<<NR, 256, 0, stream>>>(ebuf, rcur, degP, rowStartP, inv, colP, N);

    int gblocks = (N + 3) / 4;
    int ntiles = (N + 15) / 16;
    int dblocks = (ntiles + 7) / 8;   // ~2 tiles per wave

    // ---- layer 1 ----
    gather_mean_bf16<<<gblocks, 256, 0, stream>>>(xb, rowStartP, degP, colP, inv,
                                                  meanb, N);
    dense_mfma<false><<<dblocks, 256, 0, stream>>>(meanb, xb, wcat1, b1,
                                                   h1b, nullptr, nullptr, nullptr, N);
    // ---- layer 2 + head ----
    gather_mean_bf16<<<gblocks, 256, 0, stream>>>(h1b, rowStartP, degP, colP, inv,
                                                  meanb, N);
    dense_mfma<true><<<dblocks, 256, 0, stream>>>(meanb, h1b, wcat2, b2,
                                                  nullptr, whb, bh, out, N);
}

// Round 11
// 154.680 us; speedup vs baseline: 1.0606x; 1.0606x over previous
//
#include <hip/hip_runtime.h>

// GraphSAGE (2 SAGEConv mean-agg layers + linear head) on MI355X.
// N=100000 nodes, E=1600000 edges, D=64 channels, OUT=32.
//
// Round-11:
//  * gather reverted to 8-deep (16-deep regressed, r10) + VALU diet:
//    saddr 32-bit offset addressing (1 add vs 64-bit pair add) and
//    float2/v_pk_add_f32 packed accumulate (1 op vs 2).
//  * bin+prep fusion, fixed-capacity CSR, dense MFMA unchanged (verified).

#define D 64
#define OUTD 32
#define REG_SHIFT 8
#define REG_SIZE 256
#define BCHUNK 4096
#define PADQ 16                  // pad node lists to multiple of 16
#define CAP 5120                 // ebuf capacity per region (mean 4092, sigma 64)
#define OUTCAP 8960              // colP capacity per region

// ---------------- workspace layout (int units), ~61.7 MB of 256 MiB ----------------
#define OFF_FLAG     0          // 64
#define OFF_RCUR     64         // 512
#define OFF_DEG      576        // N padded-deg (reserve 100352)
#define OFF_ROWSTART 100928     // N
#define OFF_INV      201280     // N floats
#define OFF_COL      301632     // 391*OUTCAP = 3503360
#define OFF_EBUF     3804992    // 391*CAP = 2001920
#define OFF_XB       5806912    // (N+1)*32
#define OFF_H1B      9006944    // (N+1)*32
#define OFF_MEANB    12206976   // N*32
#define OFF_WC1      15406976   // 4096
#define OFF_WC2      15411072   // 4096
#define OFF_WHB      15415168   // 1024

typedef __attribute__((ext_vector_type(8))) short bf16x8;
typedef __attribute__((ext_vector_type(4))) float f32x4;
typedef __attribute__((ext_vector_type(2))) float f32x2;

__device__ __forceinline__ unsigned short bf16rne(float x) {
    unsigned u = __float_as_uint(x);
    unsigned r = (u + 0x7FFFu + ((u >> 16) & 1u)) >> 16;
    return (unsigned short)r;
}

// Detect int64-vs-int32 edge layout + init per-region cursors to r*CAP.
__global__ void detect_init(const int* __restrict__ e32, int* __restrict__ flag,
                            int* __restrict__ rcur, int NR) {
    int t = threadIdx.x;                 // 512 threads
    if (t < 64) {
        int v = e32[2 * t + 1];
        unsigned long long m = __ballot(v != 0);
        if (t == 0) flag[0] = (m == 0ULL) ? 1 : 0;   // 1 => int64 layout
    }
    if (t < NR) rcur[t] = t * CAP;
}

// Fused: blocks < bblocks bin edges into region segments; the rest do prep
// (fp32->bf16 cast of x, zero rows, weight concat). Independent outputs.
__global__ __launch_bounds__(256) void bin_prep(
        const int* __restrict__ e32, const int* __restrict__ flag,
        int* __restrict__ rcur, int* __restrict__ ebuf, int E, int NR, int bblocks,
        const float* __restrict__ x, unsigned short* __restrict__ xb,
        unsigned short* __restrict__ h1b,
        const float* __restrict__ w1l, const float* __restrict__ w1r,
        const float* __restrict__ w2l, const float* __restrict__ w2r,
        const float* __restrict__ wh,
        unsigned short* __restrict__ wcat1, unsigned short* __restrict__ wcat2,
        unsigned short* __restrict__ whb, int n4, int N) {
    __shared__ int stage[BCHUNK];
    __shared__ unsigned short rgn[BCHUNK];
    __shared__ int hist[512], lbase[512], startr[512], s1[512];
    int t = threadIdx.x;

    if (blockIdx.x >= bblocks) {
        // ---------------- prep path ----------------
        int i = (blockIdx.x - bblocks) * 256 + t;
        if (i < n4) {
            float4 v = ((const float4*)x)[i];
            unsigned lo = (unsigned)bf16rne(v.x) | ((unsigned)bf16rne(v.y) << 16);
            unsigned hi = (unsigned)bf16rne(v.z) | ((unsigned)bf16rne(v.w) << 16);
            ((uint2*)xb)[i] = make_uint2(lo, hi);
            return;
        }
        int j = i - n4;
        if (j < 16) {
            ((uint2*)xb)[(size_t)N * 16 + j] = make_uint2(0u, 0u);
        } else if (j < 32) {
            ((uint2*)h1b)[(size_t)N * 16 + (j - 16)] = make_uint2(0u, 0u);
        } else if (j < 32 + 8192) {
            int q = j - 32;
            int o = q >> 7, k = q & 127;
            wcat1[q] = bf16rne(k < 64 ? w1l[o * 64 + k] : w1r[o * 64 + k - 64]);
        } else if (j < 32 + 16384) {
            int q = j - 32 - 8192;
            int o = q >> 7, k = q & 127;
            wcat2[q] = bf16rne(k < 64 ? w2l[o * 64 + k] : w2r[o * 64 + k - 64]);
        } else if (j < 32 + 16384 + 2048) {
            int q = j - 32 - 16384;
            whb[q] = bf16rne(wh[q]);
        }
        return;
    }

    // ---------------- bin path ----------------
    int mode = flag[0];
    int base = blockIdx.x * BCHUNK;
    for (int i = t; i < 512; i += 256) hist[i] = 0;
    __syncthreads();
    for (int j = t; j < BCHUNK; j += 256) {
        int i = base + j;
        if (i < E) {
            int d = mode ? e32[2 * (E + i)] : e32[E + i];
            atomicAdd(&hist[d >> REG_SHIFT], 1);
        }
    }
    __syncthreads();
    {
        int* a = lbase; int* b = s1;
        for (int i = t; i < 512; i += 256) a[i] = hist[i];
        __syncthreads();
        for (int off = 1; off < 512; off <<= 1) {
            for (int i = t; i < 512; i += 256)
                b[i] = a[i] + ((i >= off) ? a[i - off] : 0);
            __syncthreads();
            int* tmp = a; a = b; b = tmp;
        }
        for (int i = t; i < 512; i += 256) {
            int incl = a[i];
            int ex = incl - hist[i];
            __syncthreads();
            lbase[i] = ex;
        }
        __syncthreads();
    }
    for (int i = t; i < 512; i += 256) {
        int st = 0;
        if (i < NR && hist[i] > 0) {
            st = atomicAdd(&rcur[i], hist[i]);
            int lim = (i + 1) * CAP - hist[i];
            if (st > lim) st = lim;            // safety clamp (won't trigger)
        }
        startr[i] = st;
    }
    __syncthreads();
    for (int i = t; i < 512; i += 256) hist[i] = 0;
    __syncthreads();
    for (int j = t; j < BCHUNK; j += 256) {
        int i = base + j;
        if (i < E) {
            int s = mode ? e32[2 * i]       : e32[i];
            int d = mode ? e32[2 * (E + i)] : e32[E + i];
            int r = d >> REG_SHIFT;
            int o = atomicAdd(&hist[r], 1);
            int pos = lbase[r] + o;
            stage[pos] = ((d & (REG_SIZE - 1)) << 24) | s;
            rgn[pos] = (unsigned short)r;
        }
    }
    __syncthreads();
    int count = E - base; if (count > BCHUNK) count = BCHUNK;
    for (int i = t; i < count; i += 256) {
        int r = rgn[i];
        ebuf[startr[r] + (i - lbase[r])] = stage[i];
    }
}

// Per-region local CSR build with zero-row padding (byte offsets, x16 pad).
__global__ __launch_bounds__(256) void build_csr(
        const int* __restrict__ ebuf, const int* __restrict__ rcur,
        int* __restrict__ degP, int* __restrict__ rowStartP, float* __restrict__ inv,
        int* __restrict__ colP, int N) {
    __shared__ int hist[REG_SIZE], cur[REG_SIZE], sA[REG_SIZE], sB[REG_SIZE];
    int r = blockIdx.x;
    int t = threadIdx.x;
    int lo = r << REG_SHIFT;
    int e0 = r * CAP, e1 = rcur[r];
    int colPbase = r * OUTCAP;
    hist[t] = 0;
    __syncthreads();
    for (int i = e0 + t; i < e1; i += 256)
        atomicAdd(&hist[((unsigned)ebuf[i]) >> 24], 1);
    __syncthreads();
    int v = hist[t];
    int vp = (v + PADQ - 1) & ~(PADQ - 1);
    int* a = sA; int* b = sB;
    a[t] = vp;
    __syncthreads();
    for (int off = 1; off < 256; off <<= 1) {
        b[t] = a[t] + ((t >= off) ? a[t - off] : 0);
        __syncthreads();
        int* tmp = a; a = b; b = tmp;
    }
    int startP = colPbase + (a[t] - vp);
    int node = lo + t;
    if (node < N) {
        degP[node] = vp;
        rowStartP[node] = startP;
        inv[node] = 1.0f / (float)(v > 0 ? v : 1);
    }
    cur[t] = startP;
    __syncthreads();
    for (int i = e0 + t; i < e1; i += 256) {
        int p = ebuf[i];
        int pos = atomicAdd(&cur[((unsigned)p) >> 24], 1);
        colP[pos] = (p & 0xFFFFFF) << 7;        // byte offset
    }
    __syncthreads();
    int zoff = N << 7;
    for (int k = startP + v; k < startP + vp; ++k) colP[k] = zoff;
}

// Gather: one node per wave. Dword-pair loads: lanes 0-31 cover the even
// neighbor's 128B row, lanes 32-63 the odd one's (uint = 2 channels/lane).
// 8 loads in flight (round-9 structure). saddr addressing: uniform hb base +
// 32-bit per-lane offset. Packed f32x2 accumulate (v_pk_add_f32).
__global__ __launch_bounds__(256, 8) void gather_mean_bf16(
        const unsigned short* __restrict__ hb, const int* __restrict__ rowStartP,
        const int* __restrict__ degPv, const int* __restrict__ colP,
        const float* __restrict__ invdeg, unsigned short* __restrict__ meanb,
        int n) {
    int wid = (blockIdx.x * 256 + (int)threadIdx.x) >> 6;
    int lane = threadIdx.x & 63;
    if (wid >= n) return;
    int node = __builtin_amdgcn_readfirstlane(wid);

    int rs = rowStartP[node];
    int dgp = degPv[node];
    const char* hbC = (const char*)hb;     // uniform base (SGPR pair)
    int half = lane >> 5, l31 = lane & 31;
    unsigned voff = (unsigned)(l31 << 2);

    f32x2 a0 = {0.f, 0.f}, a1 = {0.f, 0.f}, a2 = {0.f, 0.f}, a3 = {0.f, 0.f};
    f32x2 a4 = {0.f, 0.f}, a5 = {0.f, 0.f}, a6 = {0.f, 0.f}, a7 = {0.f, 0.f};

    for (int base = 0; base < dgp; base += 64) {
        int cv = colP[rs + base + lane];
        int m = dgp - base; if (m > 64) m = 64;
        int pairs = m >> 1;                 // multiple of 8
        int pb = half;                      // shfl index base: 2*p + half
        for (int p = 0; p < pairs; p += 8) {
#define G(j, A) { \
            int cb = __shfl(cv, pb + 2 * (j)); \
            unsigned u = *(const unsigned*)(hbC + ((unsigned)cb + voff)); \
            f32x2 w = {__uint_as_float(u << 16), __uint_as_float(u & 0xFFFF0000u)}; \
            A += w; }
            G(0, a0)  G(1, a1)  G(2, a2)  G(3, a3)
            G(4, a4)  G(5, a5)  G(6, a6)  G(7, a7)
#undef G
            pb += 16;
        }
    }
    f32x2 s = ((a0 + a1) + (a2 + a3)) + ((a4 + a5) + (a6 + a7));
    float s0 = s.x + __shfl_xor(s.x, 32);
    float s1 = s.y + __shfl_xor(s.y, 32);
    float iv = invdeg[node];
    if (!half) {
        unsigned mo = (unsigned)bf16rne(s0 * iv) | ((unsigned)bf16rne(s1 * iv) << 16);
        ((unsigned*)meanb)[(size_t)node * 32 + l31] = mo;
    }
}

// Dense via MFMA (verified rounds 5-10). One 16-node tile per wave iteration.
template <bool HEAD>
__global__ __launch_bounds__(256, 2) void dense_mfma(
        const unsigned short* __restrict__ meanb,
        const unsigned short* __restrict__ ownb,
        const unsigned short* __restrict__ wcat,   // [64][128]
        const float* __restrict__ bias,            // [64]
        unsigned short* __restrict__ houtb,        // !HEAD out (bf16)
        const unsigned short* __restrict__ whb,    // [32][64]
        const float* __restrict__ bh,              // [32]
        float* __restrict__ outp,                  // [N][32]
        int n) {
    const int lane = threadIdx.x & 63;
    const int wave = threadIdx.x >> 6;
    const int l15 = lane & 15;
    const int kg  = lane >> 4;

    bf16x8 Bf[4][4];
#pragma unroll
    for (int nt = 0; nt < 4; ++nt)
#pragma unroll
        for (int s = 0; s < 4; ++s)
            Bf[nt][s] = *(const bf16x8*)(wcat + (nt * 16 + l15) * 128 + s * 32 + kg * 8);

    float biasc[4];
#pragma unroll
    for (int nt = 0; nt < 4; ++nt) biasc[nt] = bias[nt * 16 + l15];

    bf16x8 Hf[2][2];
    float bhc[2];
    if constexpr (HEAD) {
#pragma unroll
        for (int nt = 0; nt < 2; ++nt) {
#pragma unroll
            for (int s = 0; s < 2; ++s)
                Hf[nt][s] = *(const bf16x8*)(whb + (nt * 16 + l15) * 64 + s * 32 + kg * 8);
            bhc[nt] = bh[nt * 16 + l15];
        }
    }

    __shared__ unsigned short hlds[HEAD ? 4 * 16 * 64 : 64];

    const int ntiles = (n + 15) >> 4;
    const int stride = gridDim.x * 4;
    int tile = blockIdx.x * 4 + wave;
    if (tile >= ntiles) return;

    bf16x8 Ac[4], An[4];
    {
        int row = tile * 16 + l15; if (row >= n) row = n - 1;
        const unsigned short* mrow = meanb + (size_t)row * 64 + kg * 8;
        const unsigned short* orow = ownb  + (size_t)row * 64 + kg * 8;
        Ac[0] = *(const bf16x8*)(mrow);
        Ac[1] = *(const bf16x8*)(mrow + 32);
        Ac[2] = *(const bf16x8*)(orow);
        Ac[3] = *(const bf16x8*)(orow + 32);
    }

    while (true) {
        int nxt = tile + stride;
        bool hasNext = nxt < ntiles;
        if (hasNext) {
            int row = nxt * 16 + l15; if (row >= n) row = n - 1;
            const unsigned short* mrow = meanb + (size_t)row * 64 + kg * 8;
            const unsigned short* orow = ownb  + (size_t)row * 64 + kg * 8;
            An[0] = *(const bf16x8*)(mrow);
            An[1] = *(const bf16x8*)(mrow + 32);
            An[2] = *(const bf16x8*)(orow);
            An[3] = *(const bf16x8*)(orow + 32);
        }

        f32x4 acc[4];
#pragma unroll
        for (int nt = 0; nt < 4; ++nt) {
            f32x4 a = {biasc[nt], biasc[nt], biasc[nt], biasc[nt]};
            a = __builtin_amdgcn_mfma_f32_16x16x32_bf16(Ac[0], Bf[nt][0], a, 0, 0, 0);
            a = __builtin_amdgcn_mfma_f32_16x16x32_bf16(Ac[1], Bf[nt][1], a, 0, 0, 0);
            a = __builtin_amdgcn_mfma_f32_16x16x32_bf16(Ac[2], Bf[nt][2], a, 0, 0, 0);
            a = __builtin_amdgcn_mfma_f32_16x16x32_bf16(Ac[3], Bf[nt][3], a, 0, 0, 0);
            acc[nt] = a;
        }

        int nb = tile * 16;
        if constexpr (!HEAD) {
#pragma unroll
            for (int nt = 0; nt < 4; ++nt)
#pragma unroll
                for (int r = 0; r < 4; ++r) {
                    int row = nb + kg * 4 + r;
                    float h = fmaxf(acc[nt][r], 0.0f);
                    if (row < n) houtb[(size_t)row * 64 + nt * 16 + l15] = bf16rne(h);
                }
        } else {
            unsigned short* L = hlds + wave * 1024;
            int n7 = lane & 7;
#pragma unroll
            for (int nt = 0; nt < 4; ++nt) {
                int bGlob = nt * 2 + (l15 >> 3);
#pragma unroll
                for (int r = 0; r < 4; ++r) {
                    int m = kg * 4 + r;
                    float h = fmaxf(acc[nt][r], 0.0f);
                    L[m * 64 + ((bGlob ^ (m & 7)) * 8) + n7] = bf16rne(h);
                }
            }
            __builtin_amdgcn_wave_barrier();
            bf16x8 hA[2];
#pragma unroll
            for (int s = 0; s < 2; ++s) {
                int kb = s * 4 + kg;
                hA[s] = *(const bf16x8*)(L + l15 * 64 + ((kb ^ (l15 & 7)) * 8));
            }
            __builtin_amdgcn_wave_barrier();
            f32x4 acc2[2];
#pragma unroll
            for (int nt = 0; nt < 2; ++nt) {
                f32x4 a = {bhc[nt], bhc[nt], bhc[nt], bhc[nt]};
                a = __builtin_amdgcn_mfma_f32_16x16x32_bf16(hA[0], Hf[nt][0], a, 0, 0, 0);
                a = __builtin_amdgcn_mfma_f32_16x16x32_bf16(hA[1], Hf[nt][1], a, 0, 0, 0);
                acc2[nt] = a;
            }
#pragma unroll
            for (int nt = 0; nt < 2; ++nt)
#pragma unroll
                for (int r = 0; r < 4; ++r) {
                    int row = nb + kg * 4 + r;
                    if (row < n) outp[(size_t)row * 32 + nt * 16 + l15] = acc2[nt][r];
                }
        }

        if (!hasNext) break;
        tile = nxt;
#pragma unroll
        for (int q = 0; q < 4; ++q) Ac[q] = An[q];
    }
}

extern "C" void kernel_launch(void* const* d_in, const int* in_sizes, int n_in,
                              void* d_out, int out_size, void* d_ws, size_t ws_size,
                              hipStream_t stream) {
    const float* x   = (const float*)d_in[0];
    const int* edges = (const int*)d_in[1];
    const float* w1l = (const float*)d_in[2];
    const float* b1  = (const float*)d_in[3];
    const float* w1r = (const float*)d_in[4];
    const float* w2l = (const float*)d_in[5];
    const float* b2  = (const float*)d_in[6];
    const float* w2r = (const float*)d_in[7];
    const float* wh  = (const float*)d_in[8];
    const float* bh  = (const float*)d_in[9];
    float* out = (float*)d_out;

    const int N = in_sizes[0] / D;   // 100000
    const int E = in_sizes[1] / 2;   // 1600000
    const int NR = (N + REG_SIZE - 1) >> REG_SHIFT;   // 391

    int* ws = (int*)d_ws;
    int*            flag     = ws + OFF_FLAG;
    int*            rcur     = ws + OFF_RCUR;
    int*            degP     = ws + OFF_DEG;
    int*            rowStartP= ws + OFF_ROWSTART;
    float*          inv      = (float*)(ws + OFF_INV);
    int*            colP     = ws + OFF_COL;
    int*            ebuf     = ws + OFF_EBUF;
    unsigned short* xb       = (unsigned short*)(ws + OFF_XB);
    unsigned short* h1b      = (unsigned short*)(ws + OFF_H1B);
    unsigned short* meanb    = (unsigned short*)(ws + OFF_MEANB);
    unsigned short* wcat1    = (unsigned short*)(ws + OFF_WC1);
    unsigned short* wcat2    = (unsigned short*)(ws + OFF_WC2);
    unsigned short* whb      = (unsigned short*)(ws + OFF_WHB);

    // ---- CSR build + prep (bin and prep fused into one dispatch) ----
    detect_init<<<1, 512, 0, stream>>>(edges, flag, rcur, NR);
    int bblocks = (E + BCHUNK - 1) / BCHUNK;                  // 391
    int n4 = N * D / 4;
    int pblocks = (n4 + 32 + 16384 + 2048 + 255) / 256;       // ~6323
    bin_prep<<<bblocks + pblocks, 256, 0, stream>>>(
        edges, flag, rcur, ebuf, E, NR, bblocks,
        x, xb, h1b, w1l, w1r, w2l, w2r, wh, wcat1, wcat2, whb, n4, N);
    build_csr<<<NR, 256, 0, stream>>>(ebuf, rcur, degP, rowStartP, inv, colP, N);

    int gblocks = (N + 3) / 4;
    int ntiles = (N + 15) / 16;
    int dblocks = (ntiles + 7) / 8;   // ~2 tiles per wave

    // ---- layer 1 ----
    gather_mean_bf16<<<gblocks, 256, 0, stream>>>(xb, rowStartP, degP, colP, inv,
                                                  meanb, N);
    dense_mfma<false><<<dblocks, 256, 0, stream>>>(meanb, xb, wcat1, b1,
                                                   h1b, nullptr, nullptr, nullptr, N);
    // ---- layer 2 + head ----
    gather_mean_bf16<<<gblocks, 256, 0, stream>>>(h1b, rowStartP, degP, colP, inv,
                                                  meanb, N);
    dense_mfma<true><<<dblocks, 256, 0, stream>>>(meanb, h1b, wcat2, b2,
                                                  nullptr, whb, bh, out, N);
}

// Round 12
// 140.143 us; speedup vs baseline: 1.1706x; 1.1037x over previous
//
#include <hip/hip_runtime.h>

// GraphSAGE (2 SAGEConv mean-agg layers + linear head) on MI355X.
// N=100000 nodes, E=1600000 edges, D=64 channels, OUT=32.
//
// Round-12:
//  * fused_layer<HEAD>: gather (r11 loop, verified) + MFMA dense in ONE
//    kernel. 16-node tile/block; means staged in swizzled LDS; wave w
//    computes output quadrant w; head via shared swizzled LDS tile.
//    Kills 2 dispatches + meanb round-trip; dense overlaps gather.
//  * detect/bin_prep/build_csr unchanged (verified).

#define D 64
#define OUTD 32
#define REG_SHIFT 8
#define REG_SIZE 256
#define BCHUNK 4096
#define PADQ 16                  // pad node lists to multiple of 16
#define CAP 5120                 // ebuf capacity per region
#define OUTCAP 8960              // colP capacity per region

// ---------------- workspace layout (int units) ----------------
#define OFF_FLAG     0          // 64
#define OFF_RCUR     64         // 512
#define OFF_DEG      576        // N padded-deg (reserve 100352)
#define OFF_ROWSTART 100928     // N
#define OFF_INV      201280     // N floats
#define OFF_COL      301632     // 391*OUTCAP = 3503360
#define OFF_EBUF     3804992    // 391*CAP = 2001920
#define OFF_XB       5806912    // (N+1)*32
#define OFF_H1B      9006944    // (N+1)*32
#define OFF_WC1      15406976   // 4096
#define OFF_WC2      15411072   // 4096
#define OFF_WHB      15415168   // 1024

typedef __attribute__((ext_vector_type(8))) short bf16x8;
typedef __attribute__((ext_vector_type(4))) float f32x4;
typedef __attribute__((ext_vector_type(2))) float f32x2;

__device__ __forceinline__ unsigned short bf16rne(float x) {
    unsigned u = __float_as_uint(x);
    unsigned r = (u + 0x7FFFu + ((u >> 16) & 1u)) >> 16;
    return (unsigned short)r;
}

// Detect int64-vs-int32 edge layout + init per-region cursors to r*CAP.
__global__ void detect_init(const int* __restrict__ e32, int* __restrict__ flag,
                            int* __restrict__ rcur, int NR) {
    int t = threadIdx.x;                 // 512 threads
    if (t < 64) {
        int v = e32[2 * t + 1];
        unsigned long long m = __ballot(v != 0);
        if (t == 0) flag[0] = (m == 0ULL) ? 1 : 0;   // 1 => int64 layout
    }
    if (t < NR) rcur[t] = t * CAP;
}

// Fused: blocks < bblocks bin edges into region segments; the rest do prep
// (fp32->bf16 cast of x, zero rows, weight concat). Independent outputs.
__global__ __launch_bounds__(256) void bin_prep(
        const int* __restrict__ e32, const int* __restrict__ flag,
        int* __restrict__ rcur, int* __restrict__ ebuf, int E, int NR, int bblocks,
        const float* __restrict__ x, unsigned short* __restrict__ xb,
        unsigned short* __restrict__ h1b,
        const float* __restrict__ w1l, const float* __restrict__ w1r,
        const float* __restrict__ w2l, const float* __restrict__ w2r,
        const float* __restrict__ wh,
        unsigned short* __restrict__ wcat1, unsigned short* __restrict__ wcat2,
        unsigned short* __restrict__ whb, int n4, int N) {
    __shared__ int stage[BCHUNK];
    __shared__ unsigned short rgn[BCHUNK];
    __shared__ int hist[512], lbase[512], startr[512], s1[512];
    int t = threadIdx.x;

    if (blockIdx.x >= bblocks) {
        // ---------------- prep path ----------------
        int i = (blockIdx.x - bblocks) * 256 + t;
        if (i < n4) {
            float4 v = ((const float4*)x)[i];
            unsigned lo = (unsigned)bf16rne(v.x) | ((unsigned)bf16rne(v.y) << 16);
            unsigned hi = (unsigned)bf16rne(v.z) | ((unsigned)bf16rne(v.w) << 16);
            ((uint2*)xb)[i] = make_uint2(lo, hi);
            return;
        }
        int j = i - n4;
        if (j < 16) {
            ((uint2*)xb)[(size_t)N * 16 + j] = make_uint2(0u, 0u);
        } else if (j < 32) {
            ((uint2*)h1b)[(size_t)N * 16 + (j - 16)] = make_uint2(0u, 0u);
        } else if (j < 32 + 8192) {
            int q = j - 32;
            int o = q >> 7, k = q & 127;
            wcat1[q] = bf16rne(k < 64 ? w1l[o * 64 + k] : w1r[o * 64 + k - 64]);
        } else if (j < 32 + 16384) {
            int q = j - 32 - 8192;
            int o = q >> 7, k = q & 127;
            wcat2[q] = bf16rne(k < 64 ? w2l[o * 64 + k] : w2r[o * 64 + k - 64]);
        } else if (j < 32 + 16384 + 2048) {
            int q = j - 32 - 16384;
            whb[q] = bf16rne(wh[q]);
        }
        return;
    }

    // ---------------- bin path ----------------
    int mode = flag[0];
    int base = blockIdx.x * BCHUNK;
    for (int i = t; i < 512; i += 256) hist[i] = 0;
    __syncthreads();
    for (int j = t; j < BCHUNK; j += 256) {
        int i = base + j;
        if (i < E) {
            int d = mode ? e32[2 * (E + i)] : e32[E + i];
            atomicAdd(&hist[d >> REG_SHIFT], 1);
        }
    }
    __syncthreads();
    {
        int* a = lbase; int* b = s1;
        for (int i = t; i < 512; i += 256) a[i] = hist[i];
        __syncthreads();
        for (int off = 1; off < 512; off <<= 1) {
            for (int i = t; i < 512; i += 256)
                b[i] = a[i] + ((i >= off) ? a[i - off] : 0);
            __syncthreads();
            int* tmp = a; a = b; b = tmp;
        }
        for (int i = t; i < 512; i += 256) {
            int incl = a[i];
            int ex = incl - hist[i];
            __syncthreads();
            lbase[i] = ex;
        }
        __syncthreads();
    }
    for (int i = t; i < 512; i += 256) {
        int st = 0;
        if (i < NR && hist[i] > 0) {
            st = atomicAdd(&rcur[i], hist[i]);
            int lim = (i + 1) * CAP - hist[i];
            if (st > lim) st = lim;            // safety clamp (won't trigger)
        }
        startr[i] = st;
    }
    __syncthreads();
    for (int i = t; i < 512; i += 256) hist[i] = 0;
    __syncthreads();
    for (int j = t; j < BCHUNK; j += 256) {
        int i = base + j;
        if (i < E) {
            int s = mode ? e32[2 * i]       : e32[i];
            int d = mode ? e32[2 * (E + i)] : e32[E + i];
            int r = d >> REG_SHIFT;
            int o = atomicAdd(&hist[r], 1);
            int pos = lbase[r] + o;
            stage[pos] = ((d & (REG_SIZE - 1)) << 24) | s;
            rgn[pos] = (unsigned short)r;
        }
    }
    __syncthreads();
    int count = E - base; if (count > BCHUNK) count = BCHUNK;
    for (int i = t; i < count; i += 256) {
        int r = rgn[i];
        ebuf[startr[r] + (i - lbase[r])] = stage[i];
    }
}

// Per-region local CSR build with zero-row padding (byte offsets, x16 pad).
__global__ __launch_bounds__(256) void build_csr(
        const int* __restrict__ ebuf, const int* __restrict__ rcur,
        int* __restrict__ degP, int* __restrict__ rowStartP, float* __restrict__ inv,
        int* __restrict__ colP, int N) {
    __shared__ int hist[REG_SIZE], cur[REG_SIZE], sA[REG_SIZE], sB[REG_SIZE];
    int r = blockIdx.x;
    int t = threadIdx.x;
    int lo = r << REG_SHIFT;
    int e0 = r * CAP, e1 = rcur[r];
    int colPbase = r * OUTCAP;
    hist[t] = 0;
    __syncthreads();
    for (int i = e0 + t; i < e1; i += 256)
        atomicAdd(&hist[((unsigned)ebuf[i]) >> 24], 1);
    __syncthreads();
    int v = hist[t];
    int vp = (v + PADQ - 1) & ~(PADQ - 1);
    int* a = sA; int* b = sB;
    a[t] = vp;
    __syncthreads();
    for (int off = 1; off < 256; off <<= 1) {
        b[t] = a[t] + ((t >= off) ? a[t - off] : 0);
        __syncthreads();
        int* tmp = a; a = b; b = tmp;
    }
    int startP = colPbase + (a[t] - vp);
    int node = lo + t;
    if (node < N) {
        degP[node] = vp;
        rowStartP[node] = startP;
        inv[node] = 1.0f / (float)(v > 0 ? v : 1);
    }
    cur[t] = startP;
    __syncthreads();
    for (int i = e0 + t; i < e1; i += 256) {
        int p = ebuf[i];
        int pos = atomicAdd(&cur[((unsigned)p) >> 24], 1);
        colP[pos] = (p & 0xFFFFFF) << 7;        // byte offset
    }
    __syncthreads();
    int zoff = N << 7;
    for (int k = startP + v; k < startP + vp; ++k) colP[k] = zoff;
}

// Fused SAGE layer: gather (phase 1) + MFMA dense (phase 2) (+ head).
// One 16-node tile per block (4 waves). Phase 1: wave w gathers nodes
// w*4..w*4+3 with the verified r11 loop, staging packed means into a
// swizzled LDS tile. Phase 2: wave w computes output quadrant nt=w via
// 4 mfma_16x16x32 (mean frags from LDS, own frags from global = gather src).
// HEAD: h2 tile staged to shared swizzled LDS; waves 0-1 do the head MFMAs.
template <bool HEAD>
__global__ __launch_bounds__(256, 8) void fused_layer(
        const unsigned short* __restrict__ hb,       // gather + own source
        const int* __restrict__ rowStartP, const int* __restrict__ degPv,
        const int* __restrict__ colP, const float* __restrict__ invdeg,
        const unsigned short* __restrict__ wcat,     // [64][128]
        const float* __restrict__ bias,              // [64]
        unsigned short* __restrict__ houtb,          // !HEAD out (bf16)
        const unsigned short* __restrict__ whb,      // [32][64]
        const float* __restrict__ bh,                // [32]
        float* __restrict__ outp,                    // [N][32]
        int n) {
    __shared__ unsigned meanT[16 * 32];              // swizzled (16B blocks)
    __shared__ unsigned short hT[HEAD ? 16 * 64 : 64];

    const int lane = threadIdx.x & 63;
    const int w    = threadIdx.x >> 6;
    const int half = lane >> 5, l31 = lane & 31;
    const int l15  = lane & 15, kg  = lane >> 4;
    const char* hbC = (const char*)hb;
    unsigned voff = (unsigned)(l31 << 2);

    const int nb = blockIdx.x * 16;

    // ---------------- phase 1: gather 4 nodes per wave ----------------
    for (int q = 0; q < 4; ++q) {
        int node = nb + w * 4 + q;
        int nodeC = node < n ? node : n - 1;
        nodeC = __builtin_amdgcn_readfirstlane(nodeC);
        int rs = rowStartP[nodeC];
        int dgp = degPv[nodeC];

        f32x2 a0 = {0.f, 0.f}, a1 = {0.f, 0.f}, a2 = {0.f, 0.f}, a3 = {0.f, 0.f};
        f32x2 a4 = {0.f, 0.f}, a5 = {0.f, 0.f}, a6 = {0.f, 0.f}, a7 = {0.f, 0.f};

        for (int base = 0; base < dgp; base += 64) {
            int cv = colP[rs + base + lane];
            int m = dgp - base; if (m > 64) m = 64;
            int pairs = m >> 1;             // multiple of 8
            int pb = half;                  // shfl index: 2*p + half
            for (int p = 0; p < pairs; p += 8) {
#define G(j, A) { \
                int cb = __shfl(cv, pb + 2 * (j)); \
                unsigned u = *(const unsigned*)(hbC + ((unsigned)cb + voff)); \
                f32x2 ww = {__uint_as_float(u << 16), __uint_as_float(u & 0xFFFF0000u)}; \
                A += ww; }
                G(0, a0)  G(1, a1)  G(2, a2)  G(3, a3)
                G(4, a4)  G(5, a5)  G(6, a6)  G(7, a7)
#undef G
                pb += 16;
            }
        }
        f32x2 s = ((a0 + a1) + (a2 + a3)) + ((a4 + a5) + (a6 + a7));
        float s0 = s.x + __shfl_xor(s.x, 32);
        float s1 = s.y + __shfl_xor(s.y, 32);
        float iv = invdeg[nodeC];
        if (!half) {
            int local = w * 4 + q;
            unsigned mo = (unsigned)bf16rne(s0 * iv) | ((unsigned)bf16rne(s1 * iv) << 16);
            int cb = l31 >> 2;
            meanT[local * 32 + ((cb ^ (local & 7)) << 2) + (l31 & 3)] = mo;
        }
    }
    __syncthreads();

    // ---------------- phase 2: dense, wave w -> output quadrant nt=w ----------------
    const int nt = w;
    // A mean fragments from LDS (swizzle-aware ds_read_b128)
    bf16x8 Am[2];
#pragma unroll
    for (int s = 0; s < 2; ++s) {
        int cb = s * 4 + kg;
        Am[s] = *(const bf16x8*)&meanT[l15 * 32 + ((cb ^ (l15 & 7)) << 2)];
    }
    // A own fragments from global (own input == gather input in SAGEConv)
    int arow = nb + l15; if (arow >= n) arow = n - 1;
    const unsigned short* orow = hb + (size_t)arow * 64 + kg * 8;
    bf16x8 Ao0 = *(const bf16x8*)(orow);
    bf16x8 Ao1 = *(const bf16x8*)(orow + 32);
    // B fragments (transient loads, L2-resident)
    const unsigned short* wrow = wcat + (nt * 16 + l15) * 128 + kg * 8;
    bf16x8 B0 = *(const bf16x8*)(wrow);
    bf16x8 B1 = *(const bf16x8*)(wrow + 32);
    bf16x8 B2 = *(const bf16x8*)(wrow + 64);
    bf16x8 B3 = *(const bf16x8*)(wrow + 96);

    float bc = bias[nt * 16 + l15];
    f32x4 a = {bc, bc, bc, bc};
    a = __builtin_amdgcn_mfma_f32_16x16x32_bf16(Am[0], B0, a, 0, 0, 0);
    a = __builtin_amdgcn_mfma_f32_16x16x32_bf16(Am[1], B1, a, 0, 0, 0);
    a = __builtin_amdgcn_mfma_f32_16x16x32_bf16(Ao0,  B2, a, 0, 0, 0);
    a = __builtin_amdgcn_mfma_f32_16x16x32_bf16(Ao1,  B3, a, 0, 0, 0);

    if constexpr (!HEAD) {
#pragma unroll
        for (int r = 0; r < 4; ++r) {
            int rw = nb + kg * 4 + r;
            float h = fmaxf(a[r], 0.0f);
            if (rw < n) houtb[(size_t)rw * 64 + nt * 16 + l15] = bf16rne(h);
        }
    } else {
        int bGlob = nt * 2 + (l15 >> 3);
        int n7 = l15 & 7;
#pragma unroll
        for (int r = 0; r < 4; ++r) {
            int m = kg * 4 + r;
            float h = fmaxf(a[r], 0.0f);
            hT[m * 64 + ((bGlob ^ (m & 7)) * 8) + n7] = bf16rne(h);
        }
        __syncthreads();
        if (w < 2) {
            bf16x8 hA[2];
#pragma unroll
            for (int s = 0; s < 2; ++s) {
                int kb = s * 4 + kg;
                hA[s] = *(const bf16x8*)(hT + l15 * 64 + ((kb ^ (l15 & 7)) * 8));
            }
            const unsigned short* hrow = whb + (w * 16 + l15) * 64 + kg * 8;
            bf16x8 H0 = *(const bf16x8*)(hrow);
            bf16x8 H1 = *(const bf16x8*)(hrow + 32);
            float bc2 = bh[w * 16 + l15];
            f32x4 a2 = {bc2, bc2, bc2, bc2};
            a2 = __builtin_amdgcn_mfma_f32_16x16x32_bf16(hA[0], H0, a2, 0, 0, 0);
            a2 = __builtin_amdgcn_mfma_f32_16x16x32_bf16(hA[1], H1, a2, 0, 0, 0);
#pragma unroll
            for (int r = 0; r < 4; ++r) {
                int rw = nb + kg * 4 + r;
                if (rw < n) outp[(size_t)rw * 32 + w * 16 + l15] = a2[r];
            }
        }
    }
}

extern "C" void kernel_launch(void* const* d_in, const int* in_sizes, int n_in,
                              void* d_out, int out_size, void* d_ws, size_t ws_size,
                              hipStream_t stream) {
    const float* x   = (const float*)d_in[0];
    const int* edges = (const int*)d_in[1];
    const float* w1l = (const float*)d_in[2];
    const float* b1  = (const float*)d_in[3];
    const float* w1r = (const float*)d_in[4];
    const float* w2l = (const float*)d_in[5];
    const float* b2  = (const float*)d_in[6];
    const float* w2r = (const float*)d_in[7];
    const float* wh  = (const float*)d_in[8];
    const float* bh  = (const float*)d_in[9];
    float* out = (float*)d_out;

    const int N = in_sizes[0] / D;   // 100000
    const int E = in_sizes[1] / 2;   // 1600000
    const int NR = (N + REG_SIZE - 1) >> REG_SHIFT;   // 391

    int* ws = (int*)d_ws;
    int*            flag     = ws + OFF_FLAG;
    int*            rcur     = ws + OFF_RCUR;
    int*            degP     = ws + OFF_DEG;
    int*            rowStartP= ws + OFF_ROWSTART;
    float*          inv      = (float*)(ws + OFF_INV);
    int*            colP     = ws + OFF_COL;
    int*            ebuf     = ws + OFF_EBUF;
    unsigned short* xb       = (unsigned short*)(ws + OFF_XB);
    unsigned short* h1b      = (unsigned short*)(ws + OFF_H1B);
    unsigned short* wcat1    = (unsigned short*)(ws + OFF_WC1);
    unsigned short* wcat2    = (unsigned short*)(ws + OFF_WC2);
    unsigned short* whb      = (unsigned short*)(ws + OFF_WHB);

    // ---- CSR build + prep (bin and prep fused into one dispatch) ----
    detect_init<<<1, 512, 0, stream>>>(edges, flag, rcur, NR);
    int bblocks = (E + BCHUNK - 1) / BCHUNK;                  // 391
    int n4 = N * D / 4;
    int pblocks = (n4 + 32 + 16384 + 2048 + 255) / 256;       // ~6323
    bin_prep<<<bblocks + pblocks, 256, 0, stream>>>(
        edges, flag, rcur, ebuf, E, NR, bblocks,
        x, xb, h1b, w1l, w1r, w2l, w2r, wh, wcat1, wcat2, whb, n4, N);
    build_csr<<<NR, 256, 0, stream>>>(ebuf, rcur, degP, rowStartP, inv, colP, N);

    int ntiles = (N + 15) / 16;   // 6250

    // ---- layer 1 (gather + dense fused) ----
    fused_layer<false><<<ntiles, 256, 0, stream>>>(
        xb, rowStartP, degP, colP, inv, wcat1, b1,
        h1b, nullptr, nullptr, nullptr, N);
    // ---- layer 2 + head (fused) ----
    fused_layer<true><<<ntiles, 256, 0, stream>>>(
        h1b, rowStartP, degP, colP, inv, wcat2, b2,
        nullptr, whb, bh, out, N);
}